// Round 10
// baseline (18382.422 us; speedup 1.0000x reference)
//
#include <hip/hip_runtime.h>

#define N0c 100000
#define N1c 20000
#define Ec 320000
#define Tc 8
#define DINc 128
#define Hc 64
#define Cc 16

typedef __attribute__((ext_vector_type(8))) short short8;
typedef __attribute__((ext_vector_type(4))) float f32x4;
typedef uint uint_a __attribute__((may_alias));
typedef ushort ushort_a __attribute__((may_alias));
struct __align__(8) u2a { uint_a x, y; };

#define LOG2E 1.442695040888963f

__device__ __forceinline__ float sigm(float x) {
    return __builtin_amdgcn_rcpf(1.f + __builtin_amdgcn_exp2f(-LOG2E * x));
}
__device__ __forceinline__ float tanh_(float x) {
    return 2.f * __builtin_amdgcn_rcpf(1.f + __builtin_amdgcn_exp2f(-2.f * LOG2E * x)) - 1.f;
}
__device__ __forceinline__ ushort f2bf(float f) {
    uint u = __float_as_uint(f);
    uint r = u + 0x7FFF + ((u >> 16) & 1);
    return (ushort)(r >> 16);
}
__device__ __forceinline__ float bf2f(ushort u) {
    return __uint_as_float(((uint)u) << 16);
}
__device__ __forceinline__ u2a pack4(const f32x4& v) {
    u2a r;
    r.x = (uint)f2bf(v[0]) | ((uint)f2bf(v[1]) << 16);
    r.y = (uint)f2bf(v[2]) | ((uint)f2bf(v[3]) << 16);
    return r;
}

// ---------------- bucketing by dst: hist -> scan -> scatter ----------------
__global__ void dhist_kernel(const int* __restrict__ dst, int* __restrict__ hist) {
    int e = blockIdx.x * blockDim.x + threadIdx.x;
    if (e < Ec) atomicAdd(&hist[dst[e]], 1);
}

__global__ void dscan_kernel(int* __restrict__ hist) {
    __shared__ int s[N1c];
    __shared__ int psum[256];
    const int tid = threadIdx.x;
    const int CH = (N1c + 255) / 256;
    for (int i = tid; i < N1c; i += 256) s[i] = hist[i];
    __syncthreads();
    int loc = 0;
    #pragma unroll 1
    for (int j = 0; j < CH; ++j) {
        int i = tid * CH + j;
        if (i < N1c) loc += s[i];
    }
    psum[tid] = loc;
    __syncthreads();
    if (tid == 0) {
        int run = 0;
        for (int t = 0; t < 256; ++t) { int v = psum[t]; psum[t] = run; run += v; }
    }
    __syncthreads();
    int run = psum[tid];
    #pragma unroll 1
    for (int j = 0; j < CH; ++j) {
        int i = tid * CH + j;
        if (i < N1c) { int v = s[i]; s[i] = run; run += v; }
    }
    __syncthreads();
    for (int i = tid; i < N1c; i += 256) hist[i] = s[i];
}

__global__ void dscatter_kernel(const int* __restrict__ dst, int* __restrict__ cursor,
                                int* __restrict__ perm) {
    int e = blockIdx.x * blockDim.x + threadIdx.x;
    if (e < Ec) {
        int pos = atomicAdd(&cursor[dst[e]], 1);
        perm[pos] = e;
    }
}

// ---------------- weight pre-swizzle (once) --------------------------------
// wA[gm*104 + k]: k<64 = Whh^T, 64..79 = Wih^T, 80 = bias, 81..103 = 0
// wEWT[u*200 + k]: k<192 = eW^T, rest 0
__global__ void wprep_kernel(const float* __restrict__ Whh, const float* __restrict__ Wih,
                             const float* __restrict__ lb, const float* __restrict__ eW,
                             ushort* __restrict__ wA, ushort* __restrict__ wEWT) {
    const int tid = threadIdx.x;
    for (int idx = tid; idx < 256 * 104; idx += 256) {
        int gm = idx / 104, k = idx - gm * 104;
        ushort v;
        if (k < 64)       v = f2bf(Whh[k * 256 + gm]);
        else if (k < 80)  v = f2bf(Wih[(k - 64) * 256 + gm]);
        else if (k == 80) v = f2bf(lb[gm]);
        else              v = 0;
        wA[idx] = v;
    }
    for (int idx = tid; idx < 64 * 200; idx += 256) {
        int u = idx / 200, k = idx - u * 200;
        wEWT[idx] = (k < 192) ? f2bf(eW[k * 64 + u]) : (ushort)0;
    }
}

// ---------------- X pre-pack: Xb[e][t][16] bf16 (zeros for t>=len) ---------
__global__ void xprep_kernel(const float* __restrict__ ef, const float* __restrict__ st,
                             const int* __restrict__ elen, ushort* __restrict__ Xb) {
    int idx = blockIdx.x * 256 + threadIdx.x;   // = e*8 + t, grid covers Ec*8 exactly
    int e = idx >> 3, t = idx & 7;
    int len = elen[e];
    uint w[8];
    if (t < len) {
        float v[16];
        #pragma unroll
        for (int f = 0; f < 15; ++f) v[f] = ef[(size_t)e * 120 + t * 15 + f];
        v[15] = st[e * 8 + t];
        #pragma unroll
        for (int j = 0; j < 8; ++j)
            w[j] = (uint)f2bf(v[2 * j]) | ((uint)f2bf(v[2 * j + 1]) << 16);
    } else {
        #pragma unroll
        for (int j = 0; j < 8; ++j) w[j] = 0;
    }
    uint_a* dst = (uint_a*)(Xb + (size_t)idx * 16);
    #pragma unroll
    for (int j = 0; j < 8; ++j) dst[j] = w[j];
}

// ---------------- time-synchronous LSTM: 2 steps per launch ----------------
// Wave = 16-edge tile. D[256 gates x 16 edges]; A in LDS (from wA).
__global__ __launch_bounds__(512, 2)
void lstm_step_kernel(const ushort* __restrict__ wA, const ushort* __restrict__ Xb,
                      const int* __restrict__ elen,
                      ushort* __restrict__ hb, ushort* __restrict__ cb, int t0)
{
    __shared__ __align__(16) ushort sA[256 * 104];   // 53.2 KB
    __shared__ __align__(16) ushort sHB[8][16 * 72]; // 18.4 KB

    const int tid = threadIdx.x;
    for (int idx = tid; idx < 256 * 104; idx += 512) sA[idx] = wA[idx];
    __syncthreads();

    const int lane = tid & 63;
    const int wv = tid >> 6;
    const int g = lane >> 4;
    const int erow = lane & 15;
    ushort_a* myHB = (ushort_a*)sHB[wv];

    for (int tile = blockIdx.x * 8 + wv; tile < Ec / 16; tile += gridDim.x * 8) {
        const int e0 = tile * 16;
        int lenv = (lane < 16) ? elen[e0 + lane] : 0;
        const int myLen = __shfl(lenv, erow);
        int tmax = myLen;
        tmax = max(tmax, __shfl_xor(tmax, 1));
        tmax = max(tmax, __shfl_xor(tmax, 2));
        tmax = max(tmax, __shfl_xor(tmax, 4));
        tmax = max(tmax, __shfl_xor(tmax, 8));
        if (tmax <= t0) continue;

        // x fragments for t0, t0+1
        const ushort_a* xrow = (const ushort_a*)Xb + (size_t)(e0 + erow) * 128;
        short8 bxA, bxB;
        {
            short8 z = {0, 0, 0, 0, 0, 0, 0, 0};
            if (g == 2) z[0] = (short)0x3F80;  // bias column k=80
            bxA = (g < 2) ? *(const short8*)(xrow + t0 * 16 + g * 8) : z;
            bxB = (g < 2) ? *(const short8*)(xrow + (t0 + 1) * 16 + g * 8) : z;
        }

        // load h (B-fragments + C/D quads) and c (C/D quads)
        f32x4 h4[4], c4[4];
        short8 bh0, bh1;
        ushort_a* hrow = (ushort_a*)hb + (size_t)(e0 + erow) * 64;
        ushort_a* crow = (ushort_a*)cb + (size_t)(e0 + erow) * 64;
        if (t0 > 0) {
            bh0 = *(const short8*)(hrow + g * 8);
            bh1 = *(const short8*)(hrow + 32 + g * 8);
            #pragma unroll
            for (int mq = 0; mq < 4; ++mq) {
                u2a hv = *(const u2a*)(hrow + mq * 16 + g * 4);
                u2a cv = *(const u2a*)(crow + mq * 16 + g * 4);
                h4[mq][0] = bf2f((ushort)(hv.x & 0xFFFF));
                h4[mq][1] = bf2f((ushort)(hv.x >> 16));
                h4[mq][2] = bf2f((ushort)(hv.y & 0xFFFF));
                h4[mq][3] = bf2f((ushort)(hv.y >> 16));
                c4[mq][0] = bf2f((ushort)(cv.x & 0xFFFF));
                c4[mq][1] = bf2f((ushort)(cv.x >> 16));
                c4[mq][2] = bf2f((ushort)(cv.y & 0xFFFF));
                c4[mq][3] = bf2f((ushort)(cv.y >> 16));
            }
        } else {
            #pragma unroll
            for (int mq = 0; mq < 4; ++mq) {
                h4[mq] = (f32x4){0.f, 0.f, 0.f, 0.f};
                c4[mq] = (f32x4){0.f, 0.f, 0.f, 0.f};
            }
        }

        // ---- step A (t = t0) ----
        {
            const bool valid = (t0 < myLen);
            #pragma unroll
            for (int mq = 0; mq < 4; ++mq) {
                const ushort_a* aiRow = (const ushort_a*)sA + ((mq)      * 16 + erow) * 104;
                const ushort_a* afRow = (const ushort_a*)sA + ((mq + 4)  * 16 + erow) * 104;
                const ushort_a* agRow = (const ushort_a*)sA + ((mq + 8)  * 16 + erow) * 104;
                const ushort_a* aoRow = (const ushort_a*)sA + ((mq + 12) * 16 + erow) * 104;
                f32x4 aI = {0.f, 0.f, 0.f, 0.f}, aF = {0.f, 0.f, 0.f, 0.f};
                f32x4 aG = {0.f, 0.f, 0.f, 0.f}, aO = {0.f, 0.f, 0.f, 0.f};
                aI = __builtin_amdgcn_mfma_f32_16x16x32_bf16(*(const short8*)(aiRow + 64 + g * 8), bxA, aI, 0, 0, 0);
                aF = __builtin_amdgcn_mfma_f32_16x16x32_bf16(*(const short8*)(afRow + 64 + g * 8), bxA, aF, 0, 0, 0);
                aG = __builtin_amdgcn_mfma_f32_16x16x32_bf16(*(const short8*)(agRow + 64 + g * 8), bxA, aG, 0, 0, 0);
                aO = __builtin_amdgcn_mfma_f32_16x16x32_bf16(*(const short8*)(aoRow + 64 + g * 8), bxA, aO, 0, 0, 0);
                if (t0 > 0) {
                    aI = __builtin_amdgcn_mfma_f32_16x16x32_bf16(*(const short8*)(aiRow + g * 8), bh0, aI, 0, 0, 0);
                    aF = __builtin_amdgcn_mfma_f32_16x16x32_bf16(*(const short8*)(afRow + g * 8), bh0, aF, 0, 0, 0);
                    aG = __builtin_amdgcn_mfma_f32_16x16x32_bf16(*(const short8*)(agRow + g * 8), bh0, aG, 0, 0, 0);
                    aO = __builtin_amdgcn_mfma_f32_16x16x32_bf16(*(const short8*)(aoRow + g * 8), bh0, aO, 0, 0, 0);
                    aI = __builtin_amdgcn_mfma_f32_16x16x32_bf16(*(const short8*)(aiRow + 32 + g * 8), bh1, aI, 0, 0, 0);
                    aF = __builtin_amdgcn_mfma_f32_16x16x32_bf16(*(const short8*)(afRow + 32 + g * 8), bh1, aF, 0, 0, 0);
                    aG = __builtin_amdgcn_mfma_f32_16x16x32_bf16(*(const short8*)(agRow + 32 + g * 8), bh1, aG, 0, 0, 0);
                    aO = __builtin_amdgcn_mfma_f32_16x16x32_bf16(*(const short8*)(aoRow + 32 + g * 8), bh1, aO, 0, 0, 0);
                }
                #pragma unroll
                for (int r = 0; r < 4; ++r) {
                    float ig = sigm(aI[r]);
                    float fg = sigm(aF[r]);
                    float gg = tanh_(aG[r]);
                    float og = sigm(aO[r]);
                    float cn = fg * c4[mq][r] + ig * gg;
                    float hn = og * tanh_(cn);
                    if (valid) { c4[mq][r] = cn; h4[mq][r] = hn; }
                }
                *(u2a*)(myHB + erow * 72 + mq * 16 + g * 4) = pack4(h4[mq]);
                __builtin_amdgcn_sched_barrier(0);
            }
        }

        // ---- step B (t = t0+1) ----
        if (tmax > t0 + 1) {
            short8 nh0 = *(const short8*)(myHB + erow * 72 + g * 8);
            short8 nh1 = *(const short8*)(myHB + erow * 72 + 32 + g * 8);
            const bool valid = (t0 + 1 < myLen);
            #pragma unroll
            for (int mq = 0; mq < 4; ++mq) {
                const ushort_a* aiRow = (const ushort_a*)sA + ((mq)      * 16 + erow) * 104;
                const ushort_a* afRow = (const ushort_a*)sA + ((mq + 4)  * 16 + erow) * 104;
                const ushort_a* agRow = (const ushort_a*)sA + ((mq + 8)  * 16 + erow) * 104;
                const ushort_a* aoRow = (const ushort_a*)sA + ((mq + 12) * 16 + erow) * 104;
                f32x4 aI = {0.f, 0.f, 0.f, 0.f}, aF = {0.f, 0.f, 0.f, 0.f};
                f32x4 aG = {0.f, 0.f, 0.f, 0.f}, aO = {0.f, 0.f, 0.f, 0.f};
                aI = __builtin_amdgcn_mfma_f32_16x16x32_bf16(*(const short8*)(aiRow + 64 + g * 8), bxB, aI, 0, 0, 0);
                aF = __builtin_amdgcn_mfma_f32_16x16x32_bf16(*(const short8*)(afRow + 64 + g * 8), bxB, aF, 0, 0, 0);
                aG = __builtin_amdgcn_mfma_f32_16x16x32_bf16(*(const short8*)(agRow + 64 + g * 8), bxB, aG, 0, 0, 0);
                aO = __builtin_amdgcn_mfma_f32_16x16x32_bf16(*(const short8*)(aoRow + 64 + g * 8), bxB, aO, 0, 0, 0);
                aI = __builtin_amdgcn_mfma_f32_16x16x32_bf16(*(const short8*)(aiRow + g * 8), nh0, aI, 0, 0, 0);
                aF = __builtin_amdgcn_mfma_f32_16x16x32_bf16(*(const short8*)(afRow + g * 8), nh0, aF, 0, 0, 0);
                aG = __builtin_amdgcn_mfma_f32_16x16x32_bf16(*(const short8*)(agRow + g * 8), nh0, aG, 0, 0, 0);
                aO = __builtin_amdgcn_mfma_f32_16x16x32_bf16(*(const short8*)(aoRow + g * 8), nh0, aO, 0, 0, 0);
                aI = __builtin_amdgcn_mfma_f32_16x16x32_bf16(*(const short8*)(aiRow + 32 + g * 8), nh1, aI, 0, 0, 0);
                aF = __builtin_amdgcn_mfma_f32_16x16x32_bf16(*(const short8*)(afRow + 32 + g * 8), nh1, aF, 0, 0, 0);
                aG = __builtin_amdgcn_mfma_f32_16x16x32_bf16(*(const short8*)(agRow + 32 + g * 8), nh1, aG, 0, 0, 0);
                aO = __builtin_amdgcn_mfma_f32_16x16x32_bf16(*(const short8*)(aoRow + 32 + g * 8), nh1, aO, 0, 0, 0);
                #pragma unroll
                for (int r = 0; r < 4; ++r) {
                    float ig = sigm(aI[r]);
                    float fg = sigm(aF[r]);
                    float gg = tanh_(aG[r]);
                    float og = sigm(aO[r]);
                    float cn = fg * c4[mq][r] + ig * gg;
                    float hn = og * tanh_(cn);
                    if (valid) { c4[mq][r] = cn; h4[mq][r] = hn; }
                }
                __builtin_amdgcn_sched_barrier(0);
            }
        }

        // store h, c (C/D quad layout = canonical [E][64])
        #pragma unroll
        for (int mq = 0; mq < 4; ++mq) {
            *(u2a*)(hrow + mq * 16 + g * 4) = pack4(h4[mq]);
            *(u2a*)(crow + mq * 16 + g * 4) = pack4(c4[mq]);
        }
    }
}

// ---------------- edge MLP: gather + rank-1 + MFMA MLP -> m[E][64] ---------
__global__ __launch_bounds__(512, 2)
void mlp_kernel(const float* __restrict__ nf, const float* __restrict__ pw,
                const ushort* __restrict__ wEWT, const float* __restrict__ ebias,
                const int* __restrict__ src, const ushort* __restrict__ hb,
                ushort* __restrict__ mOut)
{
    __shared__ __align__(16) ushort sEWT[64 * 200];      // 25.6 KB
    __shared__ __align__(16) ushort sCat[8][16 * 200];   // 51.2 KB
    __shared__ __align__(16) float sPW[128];

    const int tid = threadIdx.x;
    for (int idx = tid; idx < 64 * 200; idx += 512) sEWT[idx] = wEWT[idx];
    if (tid < 128) sPW[tid] = pw[tid];
    __syncthreads();

    const int lane = tid & 63;
    const int wv = tid >> 6;
    const int g = lane >> 4;
    const int erow = lane & 15;
    const int e4 = lane >> 2;
    const int q = lane & 3;
    ushort_a* myCat = (ushort_a*)sCat[wv];

    for (int tile = blockIdx.x * 8 + wv; tile < Ec / 16; tile += gridDim.x * 8) {
        const int e0 = tile * 16;
        int srcv = (lane < 16) ? src[e0 + lane] : 0;

        // h_src gather + rank-1 removal -> sCat[0..127]
        {
            const int srcE = __shfl(srcv, e4);
            const float* hsrow = nf + (size_t)srcE * 128;
            float4 xs[8];
            float part = 0.f;
            #pragma unroll
            for (int i = 0; i < 8; ++i) {
                int c4i = q * 8 + i;
                xs[i] = *(const float4*)(hsrow + c4i * 4);
                float4 pv = *(const float4*)(sPW + c4i * 4);
                part += xs[i].x * pv.x + xs[i].y * pv.y + xs[i].z * pv.z + xs[i].w * pv.w;
            }
            part += __shfl_xor(part, 1);
            part += __shfl_xor(part, 2);
            #pragma unroll
            for (int i = 0; i < 8; ++i) {
                int c4i = q * 8 + i;
                float4 pv = *(const float4*)(sPW + c4i * 4);
                f32x4 hp = { xs[i].x - part * pv.x, xs[i].y - part * pv.y,
                             xs[i].z - part * pv.z, xs[i].w - part * pv.w };
                *(u2a*)(myCat + e4 * 200 + c4i * 4) = pack4(hp);
            }
        }
        // e_enc -> sCat[128..191] from final h
        {
            const ushort_a* hrow = (const ushort_a*)hb + (size_t)(e0 + erow) * 64;
            #pragma unroll
            for (int mt = 0; mt < 4; ++mt) {
                u2a v = *(const u2a*)(hrow + mt * 16 + g * 4);
                *(u2a*)(myCat + erow * 200 + 128 + mt * 16 + g * 4) = v;
            }
        }

        // MLP MFMAs
        f32x4 macc[4];
        #pragma unroll
        for (int mt = 0; mt < 4; ++mt) macc[mt] = (f32x4){0.f, 0.f, 0.f, 0.f};
        #pragma unroll
        for (int kt = 0; kt < 6; ++kt) {
            short8 bfrag = *(const short8*)(myCat + erow * 200 + kt * 32 + g * 8);
            #pragma unroll
            for (int mt = 0; mt < 4; ++mt) {
                short8 afrag = *(const short8*)((const ushort_a*)sEWT + (mt * 16 + erow) * 200 + kt * 32 + g * 8);
                macc[mt] = __builtin_amdgcn_mfma_f32_16x16x32_bf16(afrag, bfrag, macc[mt], 0, 0, 0);
            }
        }

        // relu(+bias) -> m bf16
        ushort_a* mrow = (ushort_a*)mOut + (size_t)(e0 + erow) * 64;
        #pragma unroll
        for (int mt = 0; mt < 4; ++mt) {
            float4 eb4 = *(const float4*)(ebias + mt * 16 + g * 4);
            f32x4 v = { fmaxf(macc[mt][0] + eb4.x, 0.f), fmaxf(macc[mt][1] + eb4.y, 0.f),
                        fmaxf(macc[mt][2] + eb4.z, 0.f), fmaxf(macc[mt][3] + eb4.w, 0.f) };
            *(u2a*)(mrow + mt * 16 + g * 4) = pack4(v);
        }
    }
}

// ---------------- Node kernel: segment-sum of m + node math ----------------
#define NB_WAVES 8
#define NB_THREADS (NB_WAVES * 64)
__global__ __launch_bounds__(NB_THREADS, 1)
void node_kernel(const float* __restrict__ nf,
                 const float* __restrict__ sgn,
                 const float* __restrict__ eW,
                 const float* __restrict__ ebias,
                 const float* __restrict__ nW,
                 const float* __restrict__ nbias,
                 const float* __restrict__ fcW,
                 const float* __restrict__ fcb,
                 const int* __restrict__ lnid,
                 const int* __restrict__ hist,
                 const int* __restrict__ perm,
                 const ushort* __restrict__ m,
                 float* __restrict__ out,
                 int nWavesTotal)
{
    __shared__ float sEW[128 * 64];
    __shared__ float sNW[192 * 64];
    __shared__ float sFC[64 * 16];
    __shared__ float sCat[NB_WAVES][192];
    __shared__ float sAct[NB_WAVES][64];

    const int tid = threadIdx.x;
    for (int idx = tid; idx < 128 * 64; idx += NB_THREADS) sEW[idx] = eW[idx];
    for (int idx = tid; idx < 192 * 64; idx += NB_THREADS) sNW[idx] = nW[idx];
    for (int idx = tid; idx < 64 * 16; idx += NB_THREADS) sFC[idx] = fcW[idx];
    __syncthreads();

    const int lane = tid & 63;
    const int wv = tid >> 6;
    const int gwave = blockIdx.x * NB_WAVES + wv;

    const float ebv = ebias[lane];
    const float nbv = nbias[lane];
    const float fcbv = (lane < 16) ? fcb[lane] : 0.f;

    for (int n = gwave; n < N1c; n += nWavesTotal) {
        const int nid = lnid[n];
        float sh0 = nf[(size_t)nid * 128 + lane];
        float sh1 = nf[(size_t)nid * 128 + 64 + lane];
        sCat[wv][lane] = sh0;
        sCat[wv][64 + lane] = sh1;

        float tmp = ebv;
        #pragma unroll 8
        for (int cc = 0; cc < 128; ++cc) tmp += sCat[wv][cc] * sEW[cc * 64 + lane];

        const int o0 = (n == 0) ? 0 : hist[n - 1];
        const int o1 = hist[n];
        float av = 0.f;
        for (int base = o0; base < o1; base += 64) {
            int cnt = min(64, o1 - base);
            int pk = (lane < cnt) ? perm[base + lane] : 0;
            for (int j = 0; j < cnt; ++j) {
                int pe = __shfl(pk, j);
                av += bf2f(m[(size_t)pe * 64 + lane]);
            }
        }

        float hu = (av - tmp) * sgn[n];
        sCat[wv][128 + lane] = hu;

        float acc = nbv;
        #pragma unroll 8
        for (int cc = 0; cc < 192; ++cc) acc += sCat[wv][cc] * sNW[cc * 64 + lane];
        acc = fmaxf(acc, 0.f);
        sAct[wv][lane] = acc;

        if (lane < 16) {
            float o = fcbv;
            #pragma unroll
            for (int j = 0; j < 64; ++j) o += sAct[wv][j] * sFC[j * 16 + lane];
            out[(size_t)n * 16 + lane] = o;
        }
    }
}

extern "C" void kernel_launch(void* const* d_in, const int* in_sizes, int n_in,
                              void* d_out, int out_size, void* d_ws, size_t ws_size,
                              hipStream_t stream) {
    const float* nf  = (const float*)d_in[0];
    const float* ef  = (const float*)d_in[1];
    const float* st  = (const float*)d_in[2];
    const float* sgn = (const float*)d_in[3];
    const float* pw  = (const float*)d_in[4];
    const float* Wih = (const float*)d_in[5];
    const float* Whh = (const float*)d_in[6];
    const float* lb  = (const float*)d_in[7];
    const float* eW  = (const float*)d_in[8];
    const float* eb  = (const float*)d_in[9];
    const float* nW  = (const float*)d_in[10];
    const float* nb  = (const float*)d_in[11];
    const float* fcW = (const float*)d_in[12];
    const float* fcb = (const float*)d_in[13];
    const int* elen = (const int*)d_in[14];
    const int* src  = (const int*)d_in[15];
    const int* dst  = (const int*)d_in[16];
    const int* lnid = (const int*)d_in[17];

    float* out = (float*)d_out;

    // ws layout (bytes)
    char* base = (char*)d_ws;
    int*    hist = (int*)   (base + 0);            // 80 KB (pad 81920)
    int*    perm = (int*)   (base + 81920);        // 1.28 MB (pad to 1310720)
    ushort* wA   = (ushort*)(base + 1392640);      // 53.2 KB (pad 65536)
    ushort* wEWT = (ushort*)(base + 1458176);      // 25.6 KB (pad 32768)
    ushort* Xb   = (ushort*)(base + 1490944);      // 81.92 MB
    ushort* hb   = (ushort*)(base + 83410944);     // 40.96 MB
    ushort* cb   = (ushort*)(base + 124370944);    // 40.96 MB
    ushort* mbuf = (ushort*)(base + 165330944);    // 40.96 MB (end ~206.3 MB)

    hipMemsetAsync(hist, 0, 81920, stream);

    dhist_kernel<<<1250, 256, 0, stream>>>(dst, hist);
    dscan_kernel<<<1, 256, 0, stream>>>(hist);
    dscatter_kernel<<<1250, 256, 0, stream>>>(dst, hist, perm);

    wprep_kernel<<<1, 256, 0, stream>>>(Whh, Wih, lb, eW, wA, wEWT);
    xprep_kernel<<<10000, 256, 0, stream>>>(ef, st, elen, Xb);

    for (int t0 = 0; t0 < 8; t0 += 2)
        lstm_step_kernel<<<1250, 512, 0, stream>>>(wA, Xb, elen, hb, cb, t0);

    mlp_kernel<<<1250, 512, 0, stream>>>(nf, pw, wEWT, eb, src, hb, mbuf);

    node_kernel<<<512, NB_THREADS, 0, stream>>>(
        nf, sgn, eW, eb, nW, nb, fcW, fcb, lnid, hist, perm, mbuf, out,
        512 * NB_WAVES);
}

// Round 11
// 1095.978 us; speedup vs baseline: 16.7726x; 16.7726x over previous
//
#include <hip/hip_runtime.h>

#define N0c 100000
#define N1c 20000
#define Ec 320000

typedef _Float16 f16;
typedef _Float16 f16x2 __attribute__((ext_vector_type(2)));

#define LOG2E 1.442695040888963f

__device__ __forceinline__ float sigm(float x) {
    return __builtin_amdgcn_rcpf(1.f + __builtin_amdgcn_exp2f(-LOG2E * x));
}
__device__ __forceinline__ float tanh_(float x) {
    return 2.f * __builtin_amdgcn_rcpf(1.f + __builtin_amdgcn_exp2f(-2.f * LOG2E * x)) - 1.f;
}
__device__ __forceinline__ float dot2(uint w, uint v, float acc) {
#if __has_builtin(__builtin_amdgcn_fdot2)
    return __builtin_amdgcn_fdot2(__builtin_bit_cast(f16x2, w),
                                  __builtin_bit_cast(f16x2, v), acc, false);
#else
    f16x2 a = __builtin_bit_cast(f16x2, w);
    f16x2 b = __builtin_bit_cast(f16x2, v);
    return acc + (float)a[0] * (float)b[0] + (float)a[1] * (float)b[1];
#endif
}
__device__ __forceinline__ uint packh(float a, float b) {
    f16x2 p;
    p[0] = (f16)a;
    p[1] = (f16)b;
    return __builtin_bit_cast(uint, p);
}

// ---------------- bucketing by dst: hist -> scan -> scatter ----------------
__global__ void dhist_kernel(const int* __restrict__ dst, int* __restrict__ hist) {
    int e = blockIdx.x * blockDim.x + threadIdx.x;
    if (e < Ec) atomicAdd(&hist[dst[e]], 1);
}

__global__ void dscan_kernel(int* __restrict__ hist) {
    __shared__ int s[N1c];
    __shared__ int psum[256];
    const int tid = threadIdx.x;
    const int CH = (N1c + 255) / 256;
    for (int i = tid; i < N1c; i += 256) s[i] = hist[i];
    __syncthreads();
    int loc = 0;
    #pragma unroll 1
    for (int j = 0; j < CH; ++j) {
        int i = tid * CH + j;
        if (i < N1c) loc += s[i];
    }
    psum[tid] = loc;
    __syncthreads();
    if (tid == 0) {
        int run = 0;
        for (int t = 0; t < 256; ++t) { int v = psum[t]; psum[t] = run; run += v; }
    }
    __syncthreads();
    int run = psum[tid];
    #pragma unroll 1
    for (int j = 0; j < CH; ++j) {
        int i = tid * CH + j;
        if (i < N1c) { int v = s[i]; s[i] = run; run += v; }
    }
    __syncthreads();
    for (int i = tid; i < N1c; i += 256) hist[i] = s[i];
}

__global__ void dscatter_kernel(const int* __restrict__ dst, int* __restrict__ cursor,
                                int* __restrict__ perm) {
    int e = blockIdx.x * blockDim.x + threadIdx.x;
    if (e < Ec) {
        int pos = atomicAdd(&cursor[dst[e]], 1);
        perm[pos] = e;
    }
}

// ---------------- weight prep: per-lane packed f16 pair layouts ------------
// wpk (uint): idx = (r4*64 + l)*4 + i
//   r4<32: (jp=r4, g=i): pack(Whh[2jp][g*64+l], Whh[2jp+1][g*64+l])
//   r4>=32: kp=r4-32:    pack(Wih[2kp][g*64+l], Wih[2kp+1][g*64+l])
// ewc (uint): idx = (c4*64 + l)*4 + i, cp=c4*4+i: pack(eW[2cp][l], eW[2cp+1][l])
__global__ void wprep_kernel(const float* __restrict__ Whh, const float* __restrict__ Wih,
                             const float* __restrict__ eW,
                             uint* __restrict__ wpk, uint* __restrict__ ewc) {
    int idx = blockIdx.x * 256 + threadIdx.x;
    if (idx < 40 * 256) {
        int r4 = idx >> 8, l = (idx >> 2) & 63, i = idx & 3;
        uint v;
        if (r4 < 32)
            v = packh(Whh[(2 * r4) * 256 + i * 64 + l], Whh[(2 * r4 + 1) * 256 + i * 64 + l]);
        else {
            int kp = r4 - 32;
            v = packh(Wih[(2 * kp) * 256 + i * 64 + l], Wih[(2 * kp + 1) * 256 + i * 64 + l]);
        }
        wpk[idx] = v;
    }
    if (idx < 24 * 256) {
        int c4 = idx >> 8, l = (idx >> 2) & 63, i = idx & 3;
        int cp = c4 * 4 + i;
        ewc[idx] = packh(eW[(2 * cp) * 64 + l], eW[(2 * cp + 1) * 64 + l]);
    }
}

// ---------------- X pre-pack: Xpk[e][t][8] uint (f16 pairs) ----------------
__global__ void xprep_kernel(const float* __restrict__ ef, const float* __restrict__ st,
                             uint* __restrict__ Xpk) {
    int idx = blockIdx.x * 256 + threadIdx.x;   // e*8 + t
    int e = idx >> 3, t = idx & 7;
    float v[16];
    #pragma unroll
    for (int f = 0; f < 15; ++f) v[f] = ef[(size_t)e * 120 + t * 15 + f];
    v[15] = st[(size_t)e * 8 + t];
    uint* dst = Xpk + (size_t)idx * 8;
    #pragma unroll
    for (int j = 0; j < 8; ++j) dst[j] = packh(v[2 * j], v[2 * j + 1]);
}

// ---------------- LSTM: wave-per-edge, weights in registers, f16 dot2 ------
#define XD(K, XV) \
    a0 = dot2(wi[K][0], XV, a0); a1 = dot2(wi[K][1], XV, a1); \
    a2 = dot2(wi[K][2], XV, a2); a3 = dot2(wi[K][3], XV, a3);
#define HD(JP, QV) \
    a0 = dot2(wh[JP][0], QV, a0); a1 = dot2(wh[JP][1], QV, a1); \
    a2 = dot2(wh[JP][2], QV, a2); a3 = dot2(wh[JP][3], QV, a3);

__global__ __launch_bounds__(256, 2)
void lstm_kernel(const uint4* __restrict__ wpk4, const float* __restrict__ lb,
                 const uint* __restrict__ Xpk, const int* __restrict__ elen,
                 f16* __restrict__ hb)
{
    __shared__ __align__(16) f16 sH[4][64];
    const int lane = threadIdx.x & 63;
    const int wv = threadIdx.x >> 6;

    uint wh[32][4];
    uint wi[8][4];
    #pragma unroll
    for (int r4 = 0; r4 < 32; ++r4) {
        uint4 v = wpk4[r4 * 64 + lane];
        wh[r4][0] = v.x; wh[r4][1] = v.y; wh[r4][2] = v.z; wh[r4][3] = v.w;
    }
    #pragma unroll
    for (int k4 = 0; k4 < 8; ++k4) {
        uint4 v = wpk4[(32 + k4) * 64 + lane];
        wi[k4][0] = v.x; wi[k4][1] = v.y; wi[k4][2] = v.z; wi[k4][3] = v.w;
    }
    const float b0 = lb[lane], b1 = lb[64 + lane], b2 = lb[128 + lane], b3 = lb[192 + lane];

    f16* myH = sH[wv];
    const int wid = blockIdx.x * 4 + wv;
    for (int e = wid; e < Ec; e += 2048) {
        const int len = elen[e];
        const uint* xr = Xpk + (size_t)e * 64;
        uint4 xa = *(const uint4*)(xr);
        uint4 xb = *(const uint4*)(xr + 4);
        float h = 0.f, cc = 0.f;
        for (int t = 0; t < len; ++t) {
            float a0 = b0, a1 = b1, a2 = b2, a3 = b3;
            XD(0, xa.x) XD(1, xa.y) XD(2, xa.z) XD(3, xa.w)
            XD(4, xb.x) XD(5, xb.y) XD(6, xb.z) XD(7, xb.w)
            // prefetch next step's x (clamped; row always valid)
            {
                int tn = (t < 7) ? t + 1 : 7;
                xa = *(const uint4*)(xr + tn * 8);
                xb = *(const uint4*)(xr + tn * 8 + 4);
            }
            if (t > 0) {
                const uint4* hp = (const uint4*)myH;
                #pragma unroll
                for (int i = 0; i < 8; ++i) {
                    uint4 q = hp[i];
                    HD(4 * i + 0, q.x)
                    HD(4 * i + 1, q.y)
                    HD(4 * i + 2, q.z)
                    HD(4 * i + 3, q.w)
                }
            }
            float ig = sigm(a0);
            float fg = sigm(a1);
            float gg = tanh_(a2);
            float og = sigm(a3);
            cc = fg * cc + ig * gg;
            h = og * tanh_(cc);
            myH[lane] = (f16)h;   // next step's broadcast source (same-wave, no barrier)
        }
        hb[(size_t)e * 64 + lane] = (f16)h;
    }
}

// ---------------- MLP: wave-per-edge, eW in registers, f16 dot2 ------------
__global__ __launch_bounds__(256, 2)
void mlp_kernel(const float* __restrict__ nf, const float* __restrict__ pw,
                const uint4* __restrict__ ewc4, const float* __restrict__ ebias,
                const int* __restrict__ src, const f16* __restrict__ hb,
                f16* __restrict__ mbuf)
{
    __shared__ __align__(16) f16 sCat[4][192];
    const int lane = threadIdx.x & 63;
    const int wv = threadIdx.x >> 6;

    uint ew[24][4];
    #pragma unroll
    for (int i = 0; i < 24; ++i) {
        uint4 v = ewc4[i * 64 + lane];
        ew[i][0] = v.x; ew[i][1] = v.y; ew[i][2] = v.z; ew[i][3] = v.w;
    }
    const float pwl = pw[lane], pwh = pw[64 + lane];
    const float ebl = ebias[lane];

    f16* myCat = sCat[wv];
    const int wid = blockIdx.x * 4 + wv;
    for (int e = wid; e < Ec; e += 2048) {
        const int s = src[e];
        float hs0 = nf[(size_t)s * 128 + lane];
        float hs1 = nf[(size_t)s * 128 + 64 + lane];
        float part = hs0 * pwl + hs1 * pwh;
        #pragma unroll
        for (int off = 32; off; off >>= 1) part += __shfl_xor(part, off);
        float he = (float)hb[(size_t)e * 64 + lane];
        myCat[lane] = (f16)(hs0 - part * pwl);
        myCat[64 + lane] = (f16)(hs1 - part * pwh);
        myCat[128 + lane] = (f16)he;
        const uint4* cp = (const uint4*)myCat;
        float m0 = 0.f, m1 = 0.f, m2 = 0.f, m3 = 0.f;
        #pragma unroll
        for (int i = 0; i < 24; ++i) {
            uint4 q = cp[i];
            m0 = dot2(ew[i][0], q.x, m0);
            m1 = dot2(ew[i][1], q.y, m1);
            m2 = dot2(ew[i][2], q.z, m2);
            m3 = dot2(ew[i][3], q.w, m3);
        }
        float m = fmaxf(m0 + m1 + m2 + m3 + ebl, 0.f);
        mbuf[(size_t)e * 64 + lane] = (f16)m;
    }
}

// ---------------- Node kernel: segment-sum of m + node math ----------------
#define NB_WAVES 8
#define NB_THREADS (NB_WAVES * 64)
__global__ __launch_bounds__(NB_THREADS, 1)
void node_kernel(const float* __restrict__ nf,
                 const float* __restrict__ sgn,
                 const float* __restrict__ eW,
                 const float* __restrict__ ebias,
                 const float* __restrict__ nW,
                 const float* __restrict__ nbias,
                 const float* __restrict__ fcW,
                 const float* __restrict__ fcb,
                 const int* __restrict__ lnid,
                 const int* __restrict__ hist,
                 const int* __restrict__ perm,
                 const f16* __restrict__ m,
                 float* __restrict__ out,
                 int nWavesTotal)
{
    __shared__ float sEW[128 * 64];
    __shared__ float sNW[192 * 64];
    __shared__ float sFC[64 * 16];
    __shared__ float sCat[NB_WAVES][192];
    __shared__ float sAct[NB_WAVES][64];

    const int tid = threadIdx.x;
    for (int idx = tid; idx < 128 * 64; idx += NB_THREADS) sEW[idx] = eW[idx];
    for (int idx = tid; idx < 192 * 64; idx += NB_THREADS) sNW[idx] = nW[idx];
    for (int idx = tid; idx < 64 * 16; idx += NB_THREADS) sFC[idx] = fcW[idx];
    __syncthreads();

    const int lane = tid & 63;
    const int wv = tid >> 6;
    const int gwave = blockIdx.x * NB_WAVES + wv;

    const float ebv = ebias[lane];
    const float nbv = nbias[lane];
    const float fcbv = (lane < 16) ? fcb[lane] : 0.f;

    for (int n = gwave; n < N1c; n += nWavesTotal) {
        const int nid = lnid[n];
        float sh0 = nf[(size_t)nid * 128 + lane];
        float sh1 = nf[(size_t)nid * 128 + 64 + lane];
        sCat[wv][lane] = sh0;
        sCat[wv][64 + lane] = sh1;

        float tmp = ebv;
        #pragma unroll 8
        for (int cc = 0; cc < 128; ++cc) tmp += sCat[wv][cc] * sEW[cc * 64 + lane];

        const int o0 = (n == 0) ? 0 : hist[n - 1];
        const int o1 = hist[n];
        float av = 0.f;
        for (int base = o0; base < o1; base += 64) {
            int cnt = min(64, o1 - base);
            int pk = (lane < cnt) ? perm[base + lane] : 0;
            for (int j = 0; j < cnt; ++j) {
                int pe = __shfl(pk, j);
                av += (float)m[(size_t)pe * 64 + lane];
            }
        }

        float hu = (av - tmp) * sgn[n];
        sCat[wv][128 + lane] = hu;

        float acc = nbv;
        #pragma unroll 8
        for (int cc = 0; cc < 192; ++cc) acc += sCat[wv][cc] * sNW[cc * 64 + lane];
        acc = fmaxf(acc, 0.f);
        sAct[wv][lane] = acc;

        if (lane < 16) {
            float o = fcbv;
            #pragma unroll
            for (int j = 0; j < 64; ++j) o += sAct[wv][j] * sFC[j * 16 + lane];
            out[(size_t)n * 16 + lane] = o;
        }
    }
}

extern "C" void kernel_launch(void* const* d_in, const int* in_sizes, int n_in,
                              void* d_out, int out_size, void* d_ws, size_t ws_size,
                              hipStream_t stream) {
    const float* nf  = (const float*)d_in[0];
    const float* ef  = (const float*)d_in[1];
    const float* st  = (const float*)d_in[2];
    const float* sgn = (const float*)d_in[3];
    const float* pw  = (const float*)d_in[4];
    const float* Wih = (const float*)d_in[5];
    const float* Whh = (const float*)d_in[6];
    const float* lb  = (const float*)d_in[7];
    const float* eW  = (const float*)d_in[8];
    const float* eb  = (const float*)d_in[9];
    const float* nW  = (const float*)d_in[10];
    const float* nb  = (const float*)d_in[11];
    const float* fcW = (const float*)d_in[12];
    const float* fcb = (const float*)d_in[13];
    const int* elen = (const int*)d_in[14];
    const int* src  = (const int*)d_in[15];
    const int* dst  = (const int*)d_in[16];
    const int* lnid = (const int*)d_in[17];

    float* out = (float*)d_out;

    // ws layout (bytes)
    char* base = (char*)d_ws;
    int*  hist = (int*) (base + 0);           // 80 KB
    int*  perm = (int*) (base + 81920);       // 1.28 MB (pad 1310720)
    uint* wpk  = (uint*)(base + 1392640);     // 40 KB (pad 65536)
    uint* ewc  = (uint*)(base + 1458176);     // 24.5 KB (pad 32768)
    uint* Xpk  = (uint*)(base + 1490944);     // 81.92 MB
    f16*  hb   = (f16*) (base + 83410944);    // 40.96 MB
    f16*  mbuf = (f16*) (base + 124370944);   // 40.96 MB (end ~165.3 MB)

    hipMemsetAsync(hist, 0, 81920, stream);

    dhist_kernel<<<1250, 256, 0, stream>>>(dst, hist);
    dscan_kernel<<<1, 256, 0, stream>>>(hist);
    dscatter_kernel<<<1250, 256, 0, stream>>>(dst, hist, perm);

    wprep_kernel<<<40, 256, 0, stream>>>(Whh, Wih, eW, wpk, ewc);
    xprep_kernel<<<10000, 256, 0, stream>>>(ef, st, Xpk);

    lstm_kernel<<<512, 256, 0, stream>>>((const uint4*)wpk, lb, Xpk, elen, hb);
    mlp_kernel<<<512, 256, 0, stream>>>(nf, pw, (const uint4*)ewc, eb, src, hb, mbuf);

    node_kernel<<<512, NB_THREADS, 0, stream>>>(
        nf, sgn, eW, eb, nW, nb, fcW, fcb, lnid, hist, perm, mbuf, out,
        512 * NB_WAVES);
}